// Round 5
// baseline (91.324 us; speedup 1.0000x reference)
//
#include <hip/hip_runtime.h>
#include <hip/hip_bf16.h>

// AlgebraicLinear: out[m, o] = sum_i x[m, i] * w[o, i] + bias[o]
// M = 32768, K = 256 (IN_CH), N = 256 (OUT_CH), fp32 in/out, bf16 MFMA inside.

typedef __attribute__((ext_vector_type(8))) short short8;   // 8 bf16 (4 VGPRs)
typedef __attribute__((ext_vector_type(4))) short short4v;  // 4 bf16 (2 VGPRs)
typedef __attribute__((ext_vector_type(4))) float f32x4;

#define K_DIM 256
#define N_DIM 256
#define BM 128
#define THREADS 512   // 8 waves

__device__ __forceinline__ short bf16bits(float f) {
  // RNE convert via compiler (maps to v_cvt_pk_bf16_f32 when paired)
  __bf16 h = (__bf16)f;
  return __builtin_bit_cast(short, h);
}

__global__ __launch_bounds__(THREADS, 2)
void AlgebraicLinear_kernel(const float* __restrict__ x,
                            const float* __restrict__ w,
                            const float* __restrict__ bias,
                            float* __restrict__ out) {
  // bf16 x-tile, XOR-swizzled: logical (row, kbyte) lives at
  // (row*512 + kbyte) ^ ((row&7)<<4). 128 rows x 256 k x 2B = 64 KiB.
  __shared__ char lds[BM * K_DIM * 2];

  const int tid  = threadIdx.x;
  const int lane = tid & 63;
  const int wid  = tid >> 6;    // wave 0..7 -> owns n-cols [wid*32, wid*32+32)
  const int g    = lane >> 4;   // 0..3 (k-group)
  const int r    = lane & 15;

  const long mbase = (long)blockIdx.x * BM;

  // ---- W -> register B-fragments (2 n-tiles x 8 k-tiles), fp32->bf16 ----
  // B-frag lane layout: B[k = kt*32 + g*8 + i][col = nt*16 + r] = W[col][k]
  short8 bfrag[2][8];
  #pragma unroll
  for (int nt = 0; nt < 2; ++nt) {
    const float* wr = w + (size_t)(wid * 32 + nt * 16 + r) * K_DIM;
    #pragma unroll
    for (int kt = 0; kt < 8; ++kt) {
      const float4* p = reinterpret_cast<const float4*>(wr + kt * 32 + g * 8);
      float4 lo = p[0];
      float4 hi = p[1];
      short8 f;
      f[0] = bf16bits(lo.x); f[1] = bf16bits(lo.y);
      f[2] = bf16bits(lo.z); f[3] = bf16bits(lo.w);
      f[4] = bf16bits(hi.x); f[5] = bf16bits(hi.y);
      f[6] = bf16bits(hi.z); f[7] = bf16bits(hi.w);
      bfrag[nt][kt] = f;
    }
  }
  const float b0 = bias[wid * 32 + r];
  const float b1 = bias[wid * 32 + 16 + r];

  // ---- stage x tile: 128 rows x 256 fp32 -> bf16 LDS (swizzled) ----
  // chunk c = 4 consecutive floats; 64 chunks/row; consecutive tid -> coalesced 16B.
  #pragma unroll
  for (int it = 0; it < (BM * K_DIM / 4) / THREADS; ++it) {  // 16 iters
    int c   = it * THREADS + tid;
    int row = c >> 6;
    int k4  = (c & 63) * 4;
    float4 v = *reinterpret_cast<const float4*>(x + (mbase + row) * K_DIM + k4);
    short4v s;
    s[0] = bf16bits(v.x); s[1] = bf16bits(v.y);
    s[2] = bf16bits(v.z); s[3] = bf16bits(v.w);
    int addr = (row * 512 + k4 * 2) ^ ((row & 7) << 4);
    *reinterpret_cast<short4v*>(lds + addr) = s;
  }
  __syncthreads();

  // ---- compute: 8 m-tiles of 16 rows each ----
  const int ncol = wid * 32 + r;
  #pragma unroll 1
  for (int mt = 0; mt < 8; ++mt) {
    // A-frag lane layout: A[row = r][k = kt*32 + g*8 + i]
    short8 a[8];
    const int arow = mt * 16 + r;
    const int abase = arow * 512;
    const int aswz = (arow & 7) << 4;
    #pragma unroll
    for (int kt = 0; kt < 8; ++kt) {
      int addr = (abase + kt * 64 + g * 16) ^ aswz;
      a[kt] = *reinterpret_cast<const short8*>(lds + addr);
    }
    f32x4 acc0 = {0.f, 0.f, 0.f, 0.f};
    f32x4 acc1 = {0.f, 0.f, 0.f, 0.f};
    #pragma unroll
    for (int kt = 0; kt < 8; ++kt) {
      acc0 = __builtin_amdgcn_mfma_f32_16x16x32_bf16(a[kt], bfrag[0][kt], acc0, 0, 0, 0);
      acc1 = __builtin_amdgcn_mfma_f32_16x16x32_bf16(a[kt], bfrag[1][kt], acc1, 0, 0, 0);
    }
    // D layout: row = g*4 + rr, col = r (within tile)
    float* op = out + (mbase + mt * 16 + g * 4) * N_DIM + ncol;
    #pragma unroll
    for (int rr = 0; rr < 4; ++rr) {
      op[rr * N_DIM]      = acc0[rr] + b0;
      op[rr * N_DIM + 16] = acc1[rr] + b1;
    }
  }
}

extern "C" void kernel_launch(void* const* d_in, const int* in_sizes, int n_in,
                              void* d_out, int out_size, void* d_ws, size_t ws_size,
                              hipStream_t stream) {
  const float* x    = (const float*)d_in[0];  // (8, 4096, 256)
  const float* w    = (const float*)d_in[1];  // (256, 256)
  const float* bias = (const float*)d_in[2];  // (256,)
  float* out = (float*)d_out;                 // (8, 4096, 256)

  const int M = 8 * 4096;
  dim3 grid(M / BM);   // 256 blocks = 1 per CU
  dim3 block(THREADS); // 8 waves
  AlgebraicLinear_kernel<<<grid, block, 0, stream>>>(x, w, bias, out);
}